// Round 1
// baseline (984.982 us; speedup 1.0000x reference)
//
#include <hip/hip_runtime.h>

#define BATCH 16
#define CH 64
#define NPTS 65536
#define RX 32
#define RY 32
#define RZ 32
#define RVOX (RX * RY * RZ)   // 32768
#define NQ (NPTS / 4)         // 16384 float4 quads per (b, plane)

// ---------------- K1: per-batch coordinate mean (double accumulation) ----------------
__global__ void mean_kernel(const float* __restrict__ coords, double* __restrict__ meanAcc) {
    const int b = blockIdx.y;
    const int t = blockIdx.x * blockDim.x + threadIdx.x;  // [0, NQ)
    const float4* cb = (const float4*)(coords + (size_t)b * 3 * NPTS);
    double s[3];
#pragma unroll
    for (int d = 0; d < 3; ++d) {
        const float4 v = cb[d * NQ + t];
        s[d] = ((double)v.x + (double)v.y) + ((double)v.z + (double)v.w);
    }
#pragma unroll
    for (int off = 32; off > 0; off >>= 1) {
        s[0] += __shfl_down(s[0], off);
        s[1] += __shfl_down(s[1], off);
        s[2] += __shfl_down(s[2], off);
    }
    __shared__ double red[3][4];
    const int wave = threadIdx.x >> 6, lane = threadIdx.x & 63;
    if (lane == 0) { red[0][wave] = s[0]; red[1][wave] = s[1]; red[2][wave] = s[2]; }
    __syncthreads();
    if (threadIdx.x == 0) {
        double tx = 0, ty = 0, tz = 0;
        for (int w = 0; w < 4; ++w) { tx += red[0][w]; ty += red[1][w]; tz += red[2][w]; }
        atomicAdd(&meanAcc[b * 3 + 0], tx);
        atomicAdd(&meanAcc[b * 3 + 1], ty);
        atomicAdd(&meanAcc[b * 3 + 2], tz);
    }
}

// ---------------- K2: per-batch max of squared norm ----------------
__global__ void maxnorm_kernel(const float* __restrict__ coords,
                               const double* __restrict__ meanAcc,
                               int* __restrict__ maxAcc) {
    const int b = blockIdx.y;
    const int t = blockIdx.x * blockDim.x + threadIdx.x;  // [0, NQ)
    const float4* cb = (const float4*)(coords + (size_t)b * 3 * NPTS);
    const float mx = (float)(meanAcc[b * 3 + 0] * (1.0 / NPTS));
    const float my = (float)(meanAcc[b * 3 + 1] * (1.0 / NPTS));
    const float mz = (float)(meanAcc[b * 3 + 2] * (1.0 / NPTS));
    const float4 x = cb[0 * NQ + t];
    const float4 y = cb[1 * NQ + t];
    const float4 z = cb[2 * NQ + t];
    float m = 0.0f;
    {
        float dx = x.x - mx, dy = y.x - my, dz = z.x - mz; m = fmaxf(m, dx*dx + dy*dy + dz*dz);
        dx = x.y - mx; dy = y.y - my; dz = z.y - mz;      m = fmaxf(m, dx*dx + dy*dy + dz*dz);
        dx = x.z - mx; dy = y.z - my; dz = z.z - mz;      m = fmaxf(m, dx*dx + dy*dy + dz*dz);
        dx = x.w - mx; dy = y.w - my; dz = z.w - mz;      m = fmaxf(m, dx*dx + dy*dy + dz*dz);
    }
#pragma unroll
    for (int off = 32; off > 0; off >>= 1) m = fmaxf(m, __shfl_down(m, off));
    __shared__ float redm[4];
    const int wave = threadIdx.x >> 6, lane = threadIdx.x & 63;
    if (lane == 0) redm[wave] = m;
    __syncthreads();
    if (threadIdx.x == 0) {
        float tmax = fmaxf(fmaxf(redm[0], redm[1]), fmaxf(redm[2], redm[3]));
        atomicMax(&maxAcc[b], __float_as_int(tmax));  // norm2 >= 0 -> int-bit compare valid
    }
}

// ---------------- K3: per-point normalize + voxel index (u16) + counts ----------------
__global__ void point_kernel(const float* __restrict__ coords,
                             const double* __restrict__ meanAcc,
                             const int* __restrict__ maxAcc,
                             float* __restrict__ normc,
                             unsigned short* __restrict__ idx16,
                             float* __restrict__ counts) {
    const int t = blockIdx.x * blockDim.x + threadIdx.x;
    const int b = t >> 14;          // NQ = 16384 quads per plane
    const int q = t & (NQ - 1);
    const float denom = 2.0f * sqrtf(__int_as_float(maxAcc[b]));
    const float4* cb = (const float4*)(coords + (size_t)b * 3 * NPTS);
    float4* nb = (float4*)(normc + (size_t)b * 3 * NPTS);
    int vx[3][4];
#pragma unroll
    for (int d = 0; d < 3; ++d) {
        const float m = (float)(meanAcc[b * 3 + d] * (1.0 / NPTS));
        float4 v = cb[d * NQ + q];
        float4 s;
        s.x = fminf(fmaxf(((v.x - m) / denom + 0.5f) * 32.0f, 0.0f), 31.0f);
        s.y = fminf(fmaxf(((v.y - m) / denom + 0.5f) * 32.0f, 0.0f), 31.0f);
        s.z = fminf(fmaxf(((v.z - m) / denom + 0.5f) * 32.0f, 0.0f), 31.0f);
        s.w = fminf(fmaxf(((v.w - m) / denom + 0.5f) * 32.0f, 0.0f), 31.0f);
        nb[d * NQ + q] = s;
        vx[d][0] = (int)rintf(s.x);
        vx[d][1] = (int)rintf(s.y);
        vx[d][2] = (int)rintf(s.z);
        vx[d][3] = (int)rintf(s.w);
    }
    ushort4 o;
    o.x = (unsigned short)(vx[0][0] * (RY * RZ) + vx[1][0] * RZ + vx[2][0]);
    o.y = (unsigned short)(vx[0][1] * (RY * RZ) + vx[1][1] * RZ + vx[2][1]);
    o.z = (unsigned short)(vx[0][2] * (RY * RZ) + vx[1][2] * RZ + vx[2][2]);
    o.w = (unsigned short)(vx[0][3] * (RY * RZ) + vx[1][3] * RZ + vx[2][3]);
    ((ushort4*)(idx16 + (size_t)b * NPTS))[q] = o;
    float* cbp = counts + (size_t)b * RVOX;
    atomicAdd(&cbp[o.x], 1.0f);
    atomicAdd(&cbp[o.y], 1.0f);
    atomicAdd(&cbp[o.z], 1.0f);
    atomicAdd(&cbp[o.w], 1.0f);
}

// ---------------- K4: per-batch exclusive prefix sum of counts -> offs + cursor -------
// one block per batch, 1024 threads x 32 bins each.
__global__ __launch_bounds__(1024) void scan_kernel(const float* __restrict__ counts,
                                                    int* __restrict__ offs,
                                                    int* __restrict__ cursor) {
    const int b = blockIdx.x;
    const int tid = threadIdx.x;
    const float4* cb = (const float4*)(counts + (size_t)b * RVOX);
    int loc[32];
    int sum = 0;
#pragma unroll
    for (int k8 = 0; k8 < 8; ++k8) {
        const float4 c4 = cb[tid * 8 + k8];
        loc[k8 * 4 + 0] = sum; sum += (int)c4.x;
        loc[k8 * 4 + 1] = sum; sum += (int)c4.y;
        loc[k8 * 4 + 2] = sum; sum += (int)c4.z;
        loc[k8 * 4 + 3] = sum; sum += (int)c4.w;
    }
    int inc = sum;
    const int lane = tid & 63;
#pragma unroll
    for (int off = 1; off < 64; off <<= 1) {
        const int n = __shfl_up(inc, off);
        if (lane >= off) inc += n;
    }
    __shared__ int wtot[16];
    const int wid = tid >> 6;
    if (lane == 63) wtot[wid] = inc;
    __syncthreads();
    if (tid == 0) {
        int r = 0;
        for (int w = 0; w < 16; ++w) { const int t = wtot[w]; wtot[w] = r; r += t; }
    }
    __syncthreads();
    const int base = wtot[wid] + (inc - sum);
    int* ob = offs + (size_t)b * RVOX + tid * 32;
    int* ub = cursor + (size_t)b * RVOX + tid * 32;
#pragma unroll
    for (int k = 0; k < 32; ++k) { ob[k] = base + loc[k]; ub[k] = base + loc[k]; }
}

// ---------------- K5: scatter-transpose features into sorted-slot order ---------------
// block = 256 thr, handles 128 points x 64 ch. LDS tile transpose (padded, conflict-free).
// Writes ft_sorted[b'][slot][c] as one coalesced 256B wave-store per point.
__global__ __launch_bounds__(256) void scatter_kernel(const float* __restrict__ features,
                                                      const unsigned short* __restrict__ idx16,
                                                      int* __restrict__ cursor,
                                                      unsigned short* __restrict__ vsorted,
                                                      float* __restrict__ ftb, int b0) {
    const int b = b0 + blockIdx.y;
    const int n0 = blockIdx.x * 128;
    const int tid = threadIdx.x;
    __shared__ float tile[128][65];   // [point][channel], pad 65 -> stride-65 conflict-free
    __shared__ int slots[128];
    if (tid < 128) {
        const int v = idx16[(size_t)b * NPTS + n0 + tid];
        const int slot = atomicAdd(&cursor[(size_t)b * RVOX + v], 1);
        slots[tid] = slot;
        vsorted[(size_t)b * NPTS + slot] = (unsigned short)v;
    }
    const float* fb = features + ((size_t)b * CH) * NPTS + n0;
    const int j = tid & 127;
#pragma unroll
    for (int cc = 0; cc < 32; ++cc) {
        const int c = cc * 2 + (tid >> 7);
        tile[j][c] = fb[(size_t)c * NPTS + j];   // coalesced 4B/lane row reads
    }
    __syncthreads();
    const int wid = tid >> 6, lane = tid & 63;
    float* fout = ftb + ((size_t)(b - b0) * NPTS) * CH;
    for (int p = wid * 32; p < wid * 32 + 32; ++p) {
        fout[(size_t)slots[p] * CH + lane] = tile[p][lane];  // 256B coalesced wave-store
    }
}

// ---------------- K6: sorted gather-accumulate, register run-accumulation -------------
// block = 256 thr (4 waves), owns 64 voxels. Points for the chunk are contiguous in
// ft_sorted; lane = channel. Same-voxel runs accumulate in a register; one LDS
// atomic flush per run (stride-1, conflict-free). Fused divide-by-count on writeout.
__global__ __launch_bounds__(256) void gather_kernel(const float* __restrict__ ftb,
                                                     const unsigned short* __restrict__ vsorted,
                                                     const int* __restrict__ offs,
                                                     const float* __restrict__ counts,
                                                     float* __restrict__ out, int b0) {
    const int b = b0 + blockIdx.y;
    const int v0 = blockIdx.x * 64;
    const int tid = threadIdx.x;
    __shared__ float acc_t[64][65];   // [voxel][channel], padded
    for (int i = tid; i < 64 * 65; i += 256) ((float*)acc_t)[i] = 0.0f;
    __syncthreads();
    const int pstart = offs[(size_t)b * RVOX + v0];
    const int pend = (blockIdx.x == (RVOX / 64) - 1) ? NPTS
                                                     : offs[(size_t)b * RVOX + v0 + 64];
    const int wid = tid >> 6, lane = tid & 63;
    const int len = pend - pstart;
    const int s = pstart + ((len * wid) >> 2);
    const int e = pstart + ((len * (wid + 1)) >> 2);
    const unsigned short* vs = vsorted + (size_t)b * NPTS;
    const float* fb = ftb + ((size_t)(b - b0) * NPTS) * CH;
    float acc = 0.0f;
    int vcur = -1;
    for (int i = s; i < e; ++i) {
        const float f = fb[(size_t)i * CH + lane];  // 256B coalesced streaming read
        const int vox = vs[i];                      // wave-uniform broadcast load
        if (vox != vcur) {
            if (vcur >= 0) atomicAdd(&acc_t[vcur - v0][lane], acc);
            acc = 0.0f; vcur = vox;
        }
        acc += f;
    }
    if (vcur >= 0) atomicAdd(&acc_t[vcur - v0][lane], acc);
    __syncthreads();
    const float cnt = fmaxf(counts[(size_t)b * RVOX + v0 + lane], 1.0f);
    float* ob = out + ((size_t)b * CH) * RVOX + v0;
#pragma unroll
    for (int k = 0; k < 16; ++k) {
        const int c = k * 4 + wid;
        ob[(size_t)c * RVOX + lane] = acc_t[lane][c] / cnt;  // coalesced, conflict-free
    }
}

extern "C" void kernel_launch(void* const* d_in, const int* in_sizes, int n_in,
                              void* d_out, int out_size, void* d_ws, size_t ws_size,
                              hipStream_t stream) {
    const float* features = (const float*)d_in[0];  // [16, 64, 65536]
    const float* coords = (const float*)d_in[1];    // [16, 3, 65536]
    float* out = (float*)d_out;                              // [16,64,32,32,32]
    float* normc = out + (size_t)BATCH * CH * RVOX;          // [16,3,65536]

    // ws layout (bytes):
    //   [0,384)           double meanAcc[16*3]
    //   [384,448)         int maxAcc[16]
    //   [512, +2MiB)      float counts[16*32768]
    //   +2MiB             u16  idx16[16*65536]
    //   +2MiB             int  offs[16*32768]     (exclusive prefix, stable)
    //   +2MiB             int  cursor[16*32768]   (mutable copy for slot assignment)
    //   +2MiB             u16  vsorted[16*65536]  (voxel id in sorted slot order)
    //   rest              f32  ft_sorted[G][65536][64]  (16 MiB per batch in group)
    char* ws = (char*)d_ws;
    double* meanAcc = (double*)ws;
    int* maxAcc = (int*)(ws + 384);
    float* counts = (float*)(ws + 512);
    unsigned short* idx16 = (unsigned short*)(ws + 512 + 1 * 2097152);
    int* offs = (int*)(ws + 512 + 2 * 2097152);
    int* cursor = (int*)(ws + 512 + 3 * 2097152);
    unsigned short* vsorted = (unsigned short*)(ws + 512 + 4 * 2097152);
    float* ftb = (float*)(ws + 512 + 5 * 2097152);
    const size_t fixed = 512 + 5 * (size_t)2097152;         // ~10.5 MiB
    const size_t per_batch = (size_t)NPTS * CH * 4;         // 16 MiB
    int G = 1;
    if (ws_size > fixed + per_batch) {
        size_t g = (ws_size - fixed) / per_batch;
        G = (g >= BATCH) ? BATCH : (int)g;
        if (G < 1) G = 1;
    }

    hipMemsetAsync(ws, 0, 512 + 2097152, stream);  // meanAcc + maxAcc + counts

    dim3 gred(NQ / 256, BATCH);  // (64, 16)
    mean_kernel<<<gred, 256, 0, stream>>>(coords, meanAcc);
    maxnorm_kernel<<<gred, 256, 0, stream>>>(coords, meanAcc, maxAcc);
    point_kernel<<<(BATCH * NQ) / 256, 256, 0, stream>>>(coords, meanAcc, maxAcc,
                                                         normc, idx16, counts);
    scan_kernel<<<BATCH, 1024, 0, stream>>>(counts, offs, cursor);

    for (int b0 = 0; b0 < BATCH; b0 += G) {
        const int g = (BATCH - b0 < G) ? (BATCH - b0) : G;
        scatter_kernel<<<dim3(NPTS / 128, g), 256, 0, stream>>>(features, idx16, cursor,
                                                                vsorted, ftb, b0);
        gather_kernel<<<dim3(RVOX / 64, g), 256, 0, stream>>>(ftb, vsorted, offs,
                                                              counts, out, b0);
    }
}

// Round 3
// 613.518 us; speedup vs baseline: 1.6055x; 1.6055x over previous
//
#include <hip/hip_runtime.h>

#define BATCH 16
#define CH 64
#define NPTS 65536
#define RX 32
#define RY 32
#define RZ 32
#define RVOX (RX * RY * RZ)   // 32768
#define HALFVOX (RVOX / 2)    // 16384 floats = 64 KB in LDS
#define NQ (NPTS / 4)         // 16384 float4 quads per (b, plane)

// ---------------- K1: per-batch coordinate mean (double accumulation) ----------------
__global__ void mean_kernel(const float* __restrict__ coords, double* __restrict__ meanAcc) {
    const int b = blockIdx.y;
    const int t = blockIdx.x * blockDim.x + threadIdx.x;  // [0, NQ)
    const float4* cb = (const float4*)(coords + (size_t)b * 3 * NPTS);
    double s[3];
#pragma unroll
    for (int d = 0; d < 3; ++d) {
        const float4 v = cb[d * NQ + t];
        s[d] = ((double)v.x + (double)v.y) + ((double)v.z + (double)v.w);
    }
#pragma unroll
    for (int off = 32; off > 0; off >>= 1) {
        s[0] += __shfl_down(s[0], off);
        s[1] += __shfl_down(s[1], off);
        s[2] += __shfl_down(s[2], off);
    }
    __shared__ double red[3][4];
    const int wave = threadIdx.x >> 6, lane = threadIdx.x & 63;
    if (lane == 0) { red[0][wave] = s[0]; red[1][wave] = s[1]; red[2][wave] = s[2]; }
    __syncthreads();
    if (threadIdx.x == 0) {
        double tx = 0, ty = 0, tz = 0;
        for (int w = 0; w < 4; ++w) { tx += red[0][w]; ty += red[1][w]; tz += red[2][w]; }
        atomicAdd(&meanAcc[b * 3 + 0], tx);
        atomicAdd(&meanAcc[b * 3 + 1], ty);
        atomicAdd(&meanAcc[b * 3 + 2], tz);
    }
}

// ---------------- K2: per-batch max of squared norm ----------------
__global__ void maxnorm_kernel(const float* __restrict__ coords,
                               const double* __restrict__ meanAcc,
                               int* __restrict__ maxAcc) {
    const int b = blockIdx.y;
    const int t = blockIdx.x * blockDim.x + threadIdx.x;  // [0, NQ)
    const float4* cb = (const float4*)(coords + (size_t)b * 3 * NPTS);
    const float mx = (float)(meanAcc[b * 3 + 0] * (1.0 / NPTS));
    const float my = (float)(meanAcc[b * 3 + 1] * (1.0 / NPTS));
    const float mz = (float)(meanAcc[b * 3 + 2] * (1.0 / NPTS));
    const float4 x = cb[0 * NQ + t];
    const float4 y = cb[1 * NQ + t];
    const float4 z = cb[2 * NQ + t];
    float m = 0.0f;
    {
        float dx = x.x - mx, dy = y.x - my, dz = z.x - mz; m = fmaxf(m, dx*dx + dy*dy + dz*dz);
        dx = x.y - mx; dy = y.y - my; dz = z.y - mz;      m = fmaxf(m, dx*dx + dy*dy + dz*dz);
        dx = x.z - mx; dy = y.z - my; dz = z.z - mz;      m = fmaxf(m, dx*dx + dy*dy + dz*dz);
        dx = x.w - mx; dy = y.w - my; dz = z.w - mz;      m = fmaxf(m, dx*dx + dy*dy + dz*dz);
    }
#pragma unroll
    for (int off = 32; off > 0; off >>= 1) m = fmaxf(m, __shfl_down(m, off));
    __shared__ float redm[4];
    const int wave = threadIdx.x >> 6, lane = threadIdx.x & 63;
    if (lane == 0) redm[wave] = m;
    __syncthreads();
    if (threadIdx.x == 0) {
        float tmax = fmaxf(fmaxf(redm[0], redm[1]), fmaxf(redm[2], redm[3]));
        atomicMax(&maxAcc[b], __float_as_int(tmax));  // norm2 >= 0 -> int-bit compare valid
    }
}

// ---------------- K3: per-point normalize + voxel index (u16); pure streaming --------
__global__ void point_kernel(const float* __restrict__ coords,
                             const double* __restrict__ meanAcc,
                             const int* __restrict__ maxAcc,
                             float* __restrict__ normc,
                             unsigned short* __restrict__ idx16) {
    const int t = blockIdx.x * blockDim.x + threadIdx.x;
    const int b = t >> 14;          // NQ = 16384 quads per plane
    const int q = t & (NQ - 1);
    const float denom = 2.0f * sqrtf(__int_as_float(maxAcc[b]));
    const float4* cb = (const float4*)(coords + (size_t)b * 3 * NPTS);
    float4* nb = (float4*)(normc + (size_t)b * 3 * NPTS);
    int vx[3][4];
#pragma unroll
    for (int d = 0; d < 3; ++d) {
        const float m = (float)(meanAcc[b * 3 + d] * (1.0 / NPTS));
        float4 v = cb[d * NQ + q];
        float4 s;
        s.x = fminf(fmaxf(((v.x - m) / denom + 0.5f) * 32.0f, 0.0f), 31.0f);
        s.y = fminf(fmaxf(((v.y - m) / denom + 0.5f) * 32.0f, 0.0f), 31.0f);
        s.z = fminf(fmaxf(((v.z - m) / denom + 0.5f) * 32.0f, 0.0f), 31.0f);
        s.w = fminf(fmaxf(((v.w - m) / denom + 0.5f) * 32.0f, 0.0f), 31.0f);
        nb[d * NQ + q] = s;
        vx[d][0] = (int)rintf(s.x);
        vx[d][1] = (int)rintf(s.y);
        vx[d][2] = (int)rintf(s.z);
        vx[d][3] = (int)rintf(s.w);
    }
    ushort4 o;
    o.x = (unsigned short)(vx[0][0] * (RY * RZ) + vx[1][0] * RZ + vx[2][0]);
    o.y = (unsigned short)(vx[0][1] * (RY * RZ) + vx[1][1] * RZ + vx[2][1]);
    o.z = (unsigned short)(vx[0][2] * (RY * RZ) + vx[1][2] * RZ + vx[2][2]);
    o.w = (unsigned short)(vx[0][3] * (RY * RZ) + vx[1][3] * RZ + vx[2][3]);
    ((ushort4*)(idx16 + (size_t)b * NPTS))[q] = o;
}

// ---------------- K4: per-batch LDS histogram (packed u16) + scan -> cursor + counts --
__global__ __launch_bounds__(1024) void histscan_kernel(const unsigned short* __restrict__ idx16,
                                                        int* __restrict__ cursor,
                                                        float* __restrict__ counts) {
    const int b = blockIdx.x;
    const int tid = threadIdx.x;
    __shared__ unsigned int h32[RVOX / 2];  // 64 KB, two u16 counters per word
#pragma unroll
    for (int k = 0; k < RVOX / 2 / 1024; ++k) h32[tid + k * 1024] = 0u;
    __syncthreads();
    const ushort4* q = (const ushort4*)(idx16 + (size_t)b * NPTS);
#pragma unroll
    for (int k = 0; k < NPTS / 4 / 1024; ++k) {
        const ushort4 v = q[tid + k * 1024];
        atomicAdd(&h32[v.x >> 1], 1u << ((v.x & 1) * 16));
        atomicAdd(&h32[v.y >> 1], 1u << ((v.y & 1) * 16));
        atomicAdd(&h32[v.z >> 1], 1u << ((v.z & 1) * 16));
        atomicAdd(&h32[v.w >> 1], 1u << ((v.w & 1) * 16));
    }
    __syncthreads();
    int loc[32];
    int cnt[32];
    int sum = 0;
#pragma unroll
    for (int w = 0; w < 16; ++w) {
        const unsigned pw = h32[tid * 16 + w];
        const int c0 = (int)(pw & 0xffffu), c1 = (int)(pw >> 16);
        loc[2 * w] = sum; cnt[2 * w] = c0; sum += c0;
        loc[2 * w + 1] = sum; cnt[2 * w + 1] = c1; sum += c1;
    }
    int inc = sum;
    const int lane = tid & 63;
#pragma unroll
    for (int off = 1; off < 64; off <<= 1) {
        const int n = __shfl_up(inc, off);
        if (lane >= off) inc += n;
    }
    __syncthreads();                 // h32 reads done; reuse its space for wave totals
    int* wtot = (int*)h32;
    const int wid = tid >> 6;
    if (lane == 63) wtot[wid] = inc;
    __syncthreads();
    if (tid == 0) {
        int r = 0;
        for (int w = 0; w < 16; ++w) { const int t = wtot[w]; wtot[w] = r; r += t; }
    }
    __syncthreads();
    const int base = wtot[wid] + (inc - sum);
    int* ub = cursor + (size_t)b * RVOX + tid * 32;
    float* cb = counts + (size_t)b * RVOX + tid * 32;
#pragma unroll
    for (int k = 0; k < 32; ++k) { ub[k] = base + loc[k]; cb[k] = (float)cnt[k]; }
}

// ---------------- K5: scatter-transpose features into sorted-slot order ---------------
__global__ __launch_bounds__(256) void scatter_kernel(const float* __restrict__ features,
                                                      const unsigned short* __restrict__ idx16,
                                                      int* __restrict__ cursor,
                                                      unsigned short* __restrict__ vsorted,
                                                      float* __restrict__ ftb, int b0) {
    const int b = b0 + blockIdx.y;
    const int n0 = blockIdx.x * 128;
    const int tid = threadIdx.x;
    __shared__ float tile[128][65];   // [point][channel], pad 65 -> conflict-free
    __shared__ int slots[128];
    if (tid < 128) {
        const int v = idx16[(size_t)b * NPTS + n0 + tid];
        const int slot = atomicAdd(&cursor[(size_t)b * RVOX + v], 1);
        slots[tid] = slot;
        vsorted[(size_t)b * NPTS + slot] = (unsigned short)v;
    }
    const float* fb = features + ((size_t)b * CH) * NPTS + n0;
    const int j = tid & 127;
#pragma unroll
    for (int cc = 0; cc < 32; ++cc) {
        const int c = cc * 2 + (tid >> 7);
        tile[j][c] = fb[(size_t)c * NPTS + j];   // coalesced 256B wave reads
    }
    __syncthreads();
    const int wid = tid >> 6, lane = tid & 63;
    float* fout = ftb + ((size_t)(b - b0) * NPTS) * CH;
    for (int p = wid * 32; p < wid * 32 + 32; ++p) {
        fout[(size_t)slots[p] * CH + lane] = tile[p][lane];  // 256B coalesced wave-store
    }
}

// ---------------- K5b: zero only slice-boundary accumulator rows ----------------------
__global__ __launch_bounds__(256) void zero_boundary_kernel(const unsigned short* __restrict__ vsorted,
                                                            float* __restrict__ acc, int b0) {
    const int b = b0 + blockIdx.y;
    const int tid = threadIdx.x;
    const int wid = tid >> 6, lane = tid & 63;
    const int slice = blockIdx.x * 4 + wid;          // 64 blocks x 4 waves = 256 slices
    const unsigned short* vs = vsorted + (size_t)b * NPTS;
    const int v1 = vs[slice * 256];
    const int v2 = vs[slice * 256 + 255];
    float* ab = acc + ((size_t)(b - b0) * RVOX) * CH;
    ab[(size_t)v1 * CH + lane] = 0.0f;
    ab[(size_t)v2 * CH + lane] = 0.0f;
}

// ---------------- K6: balanced sorted gather, exclusive-run stores --------------------
// Each wave owns exactly 256 sorted points. 8 independent 256B row loads in flight.
// Interior voxel runs are exclusively owned -> plain coalesced store; only the two
// possibly-shared boundary runs per slice use atomicAdd onto pre-zeroed rows.
__global__ __launch_bounds__(256) void gather_kernel(const float* __restrict__ ftb,
                                                     const unsigned short* __restrict__ vsorted,
                                                     float* __restrict__ acc, int b0) {
    const int b = b0 + blockIdx.y;
    const int tid = threadIdx.x;
    const int wid = tid >> 6, lane = tid & 63;
    const int slice = blockIdx.x * 4 + wid;          // 64 blocks x 4 waves = 256 slices
    const int s = slice * 256;
    const unsigned short* vs = vsorted + (size_t)b * NPTS;
    const float* fb = ftb + ((size_t)(b - b0) * NPTS) * CH;
    float* ab = acc + ((size_t)(b - b0) * RVOX) * CH;

    int vcur = vs[s];
    float a = 0.0f;
    bool boundary = true;   // first run may be shared with the previous slice
    for (int base = s; base < s + 256; base += 8) {
        float f[8];
        const uint4 vv = *(const uint4*)(vs + base);   // 8 voxel ids, uniform 16B load
#pragma unroll
        for (int k = 0; k < 8; ++k) f[k] = fb[(size_t)(base + k) * CH + lane];
#pragma unroll
        for (int k = 0; k < 8; ++k) {
            const unsigned w = ((const unsigned*)&vv)[k >> 1];
            const int v = (int)((w >> ((k & 1) * 16)) & 0xffffu);
            if (v != vcur) {
                if (boundary) { atomicAdd(&ab[(size_t)vcur * CH + lane], a); boundary = false; }
                else          { ab[(size_t)vcur * CH + lane] = a; }
                vcur = v; a = 0.0f;
            }
            a += f[k];
        }
    }
    atomicAdd(&ab[(size_t)vcur * CH + lane], a);  // final run may continue into next slice
}

// ---------------- K7: transpose-divide acc[b][vox][c] -> out[b][c][vox] ---------------
__global__ __launch_bounds__(256) void finalize_kernel(const float* __restrict__ acc,
                                                       const float* __restrict__ counts,
                                                       float* __restrict__ out, int b0) {
    const int b = b0 + blockIdx.y;
    const int v0 = blockIdx.x * 64;
    const int tid = threadIdx.x;
    const int wid = tid >> 6, lane = tid & 63;
    __shared__ float tile[64][65];
    __shared__ float cvec[64];
    if (tid < 64) cvec[tid] = counts[(size_t)b * RVOX + v0 + tid];
    __syncthreads();
    const float* ab = acc + ((size_t)(b - b0) * RVOX + v0) * CH;
#pragma unroll
    for (int k = 0; k < 16; ++k) {
        const int row = k * 4 + wid;
        tile[row][lane] = (cvec[row] > 0.0f) ? ab[(size_t)row * CH + lane] : 0.0f;
    }
    __syncthreads();
    const float d = fmaxf(cvec[lane], 1.0f);
    float* ob = out + ((size_t)b * CH) * RVOX + v0;
#pragma unroll
    for (int k = 0; k < 16; ++k) {
        const int c = k * 4 + wid;
        ob[(size_t)c * RVOX + lane] = tile[lane][c] / d;   // coalesced, conflict-free
    }
}

// ---------------- Fallback path (proven, ~4.7 MB workspace) ---------------------------
// FB1: counts via global atomics (round-0 style)
__global__ void count_kernel(const unsigned short* __restrict__ idx16,
                             float* __restrict__ counts) {
    const int t = blockIdx.x * blockDim.x + threadIdx.x;
    const int b = t >> 14;
    const int q = t & (NQ - 1);
    const ushort4 o = ((const ushort4*)(idx16 + (size_t)b * NPTS))[q];
    float* cbp = counts + (size_t)b * RVOX;
    atomicAdd(&cbp[o.x], 1.0f);
    atomicAdd(&cbp[o.y], 1.0f);
    atomicAdd(&cbp[o.z], 1.0f);
    atomicAdd(&cbp[o.w], 1.0f);
}

// FB2: per-(b,c) LDS-privatized accumulation, 2 half-grid passes (round-0, measured 366us)
__global__ __launch_bounds__(1024) void accum_kernel(const float* __restrict__ features,
                                                     const unsigned short* __restrict__ idx16,
                                                     const float* __restrict__ counts,
                                                     float* __restrict__ out) {
    __shared__ float g[HALFVOX];  // 64 KB
    const int c = blockIdx.x;
    const int b = blockIdx.y;
    const int tid = threadIdx.x;
    const float4* fs = (const float4*)(features + ((size_t)(b * CH + c)) * NPTS);
    const ushort4* is = (const ushort4*)(idx16 + (size_t)b * NPTS);
    const float* cb = counts + (size_t)b * RVOX;
    float* ob = out + ((size_t)(b * CH + c)) * RVOX;

#pragma unroll
    for (int half = 0; half < 2; ++half) {
        for (int i = tid; i < HALFVOX; i += 1024) g[i] = 0.0f;
        __syncthreads();
        const unsigned short want = (unsigned short)half;
        for (int base = tid; base < NQ; base += 4096) {
            const float4 f0 = fs[base];
            const float4 f1 = fs[base + 1024];
            const float4 f2 = fs[base + 2048];
            const float4 f3 = fs[base + 3072];
            const ushort4 v0 = is[base];
            const ushort4 v1 = is[base + 1024];
            const ushort4 v2 = is[base + 2048];
            const ushort4 v3 = is[base + 3072];
            if ((v0.x >> 14) == want) atomicAdd(&g[v0.x & (HALFVOX - 1)], f0.x);
            if ((v0.y >> 14) == want) atomicAdd(&g[v0.y & (HALFVOX - 1)], f0.y);
            if ((v0.z >> 14) == want) atomicAdd(&g[v0.z & (HALFVOX - 1)], f0.z);
            if ((v0.w >> 14) == want) atomicAdd(&g[v0.w & (HALFVOX - 1)], f0.w);
            if ((v1.x >> 14) == want) atomicAdd(&g[v1.x & (HALFVOX - 1)], f1.x);
            if ((v1.y >> 14) == want) atomicAdd(&g[v1.y & (HALFVOX - 1)], f1.y);
            if ((v1.z >> 14) == want) atomicAdd(&g[v1.z & (HALFVOX - 1)], f1.z);
            if ((v1.w >> 14) == want) atomicAdd(&g[v1.w & (HALFVOX - 1)], f1.w);
            if ((v2.x >> 14) == want) atomicAdd(&g[v2.x & (HALFVOX - 1)], f2.x);
            if ((v2.y >> 14) == want) atomicAdd(&g[v2.y & (HALFVOX - 1)], f2.y);
            if ((v2.z >> 14) == want) atomicAdd(&g[v2.z & (HALFVOX - 1)], f2.z);
            if ((v2.w >> 14) == want) atomicAdd(&g[v2.w & (HALFVOX - 1)], f2.w);
            if ((v3.x >> 14) == want) atomicAdd(&g[v3.x & (HALFVOX - 1)], f3.x);
            if ((v3.y >> 14) == want) atomicAdd(&g[v3.y & (HALFVOX - 1)], f3.y);
            if ((v3.z >> 14) == want) atomicAdd(&g[v3.z & (HALFVOX - 1)], f3.z);
            if ((v3.w >> 14) == want) atomicAdd(&g[v3.w & (HALFVOX - 1)], f3.w);
        }
        __syncthreads();
        const float* ch = cb + half * HALFVOX;
        float* oh = ob + half * HALFVOX;
        for (int i = tid; i < HALFVOX / 4; i += 1024) {
            const float4 c4 = ((const float4*)ch)[i];
            float4 v = ((const float4*)g)[i];
            v.x /= fmaxf(c4.x, 1.0f);
            v.y /= fmaxf(c4.y, 1.0f);
            v.z /= fmaxf(c4.z, 1.0f);
            v.w /= fmaxf(c4.w, 1.0f);
            ((float4*)oh)[i] = v;
        }
        __syncthreads();
    }
}

extern "C" void kernel_launch(void* const* d_in, const int* in_sizes, int n_in,
                              void* d_out, int out_size, void* d_ws, size_t ws_size,
                              hipStream_t stream) {
    const float* features = (const float*)d_in[0];  // [16, 64, 65536]
    const float* coords = (const float*)d_in[1];    // [16, 3, 65536]
    float* out = (float*)d_out;                              // [16,64,32,32,32]
    float* normc = out + (size_t)BATCH * CH * RVOX;          // [16,3,65536]

    // ws layout (bytes):
    //   [0,384)      double meanAcc[16*3]
    //   [384,448)    int maxAcc[16]
    //   [512,+2MiB)  float counts[16*32768]
    //   +2MiB        u16  idx16[16*65536]
    //   +2MiB        int  cursor[16*32768]        (sorted path only)
    //   +2MiB        u16  vsorted[16*65536]       (sorted path only)
    //   then per group: f32 ft_sorted[g][65536][64] (16 MiB/b) + f32 acc[g][32768][64] (8 MiB/b)
    char* ws = (char*)d_ws;
    double* meanAcc = (double*)ws;
    int* maxAcc = (int*)(ws + 384);
    float* counts = (float*)(ws + 512);
    unsigned short* idx16 = (unsigned short*)(ws + 512 + 1 * 2097152);
    int* cursor = (int*)(ws + 512 + 2 * 2097152);
    unsigned short* vsorted = (unsigned short*)(ws + 512 + 3 * 2097152);
    char* grpbase = ws + 512 + 4 * 2097152;
    const size_t fixed = 512 + 4 * (size_t)2097152;                          // ~8.4 MiB
    const size_t per_batch = (size_t)NPTS * CH * 4 + (size_t)RVOX * CH * 4;  // 24 MiB

    int G = 0;  // 0 -> fallback path
    if (ws_size >= fixed + per_batch) {
        size_t g = (ws_size - fixed) / per_batch;
        G = (g >= BATCH) ? BATCH : (int)g;
    }

    dim3 gred(NQ / 256, BATCH);  // (64, 16)

    if (G >= 1) {
        hipMemsetAsync(ws, 0, 512, stream);  // meanAcc + maxAcc only
        mean_kernel<<<gred, 256, 0, stream>>>(coords, meanAcc);
        maxnorm_kernel<<<gred, 256, 0, stream>>>(coords, meanAcc, maxAcc);
        point_kernel<<<(BATCH * NQ) / 256, 256, 0, stream>>>(coords, meanAcc, maxAcc,
                                                             normc, idx16);
        histscan_kernel<<<BATCH, 1024, 0, stream>>>(idx16, cursor, counts);
        for (int b0 = 0; b0 < BATCH; b0 += G) {
            const int g = (BATCH - b0 < G) ? (BATCH - b0) : G;
            float* ftb = (float*)grpbase;
            float* acc = (float*)(grpbase + (size_t)g * NPTS * CH * 4);
            scatter_kernel<<<dim3(NPTS / 128, g), 256, 0, stream>>>(features, idx16, cursor,
                                                                    vsorted, ftb, b0);
            zero_boundary_kernel<<<dim3(64, g), 256, 0, stream>>>(vsorted, acc, b0);
            gather_kernel<<<dim3(64, g), 256, 0, stream>>>(ftb, vsorted, acc, b0);
            finalize_kernel<<<dim3(RVOX / 64, g), 256, 0, stream>>>(acc, counts, out, b0);
        }
    } else {
        // Fallback: proven round-0 path, 512 + 4 MiB workspace.
        hipMemsetAsync(ws, 0, 512 + 2097152, stream);  // meanAcc + maxAcc + counts
        mean_kernel<<<gred, 256, 0, stream>>>(coords, meanAcc);
        maxnorm_kernel<<<gred, 256, 0, stream>>>(coords, meanAcc, maxAcc);
        point_kernel<<<(BATCH * NQ) / 256, 256, 0, stream>>>(coords, meanAcc, maxAcc,
                                                             normc, idx16);
        count_kernel<<<(BATCH * NQ) / 256, 256, 0, stream>>>(idx16, counts);
        accum_kernel<<<dim3(CH, BATCH), 1024, 0, stream>>>(features, idx16, counts, out);
    }
}